// Round 1
// baseline (186.223 us; speedup 1.0000x reference)
//
#include <hip/hip_runtime.h>
#include <cstdint>

typedef unsigned long long u64;

// Dims: B=2, S=1024, C=512, H=8, hd=64, T=4.
// bits layout: [3(qkv)][4(t)][2(b)][8(h)][1024(s)] u64 (bit d = channel h*64+d)
// vt   layout: [2(b)][8(h)][4(t)][16(w)][64(d)]  u64 (bit j = k-index w*64+j)

// ---------------- Kernel A: y = x @ W^T, LIF(4 steps, constant drive), pack bits
__global__ __launch_bounds__(256) void gemm_lif_pack(
    const float* __restrict__ x,    // [2048][512]
    const float* __restrict__ Wq,
    const float* __restrict__ Wk,
    const float* __restrict__ Wv,
    u64* __restrict__ bits)
{
    const int lane = threadIdx.x & 63;
    const int wave = __builtin_amdgcn_readfirstlane(threadIdx.x >> 6);
    const int bx = blockIdx.x;   // row tile of 64 (M = 2048)
    const int by = blockIdx.y;   // head == 64-channel tile
    const int bz = blockIdx.z;   // 0=q 1=k 2=v
    const float* W = (bz == 0) ? Wq : (bz == 1) ? Wk : Wv;

    const int c  = (by << 6) + lane;          // output channel (lane = bit d)
    const int r0 = (bx << 6) + (wave << 4);   // first of 16 rows for this wave

    const float* __restrict__ wrow = W + (size_t)c * 512;
    const float* __restrict__ xrow = x + (size_t)r0 * 512;

    float acc[16];
#pragma unroll
    for (int r = 0; r < 16; ++r) acc[r] = 0.f;

    for (int k = 0; k < 512; k += 4) {
        const float4 w4 = *(const float4*)(wrow + k);
#pragma unroll
        for (int r = 0; r < 16; ++r) {
            const float4 x4 = *(const float4*)(xrow + (size_t)r * 512 + k);
            acc[r] = fmaf(x4.x, w4.x, acc[r]);
            acc[r] = fmaf(x4.y, w4.y, acc[r]);
            acc[r] = fmaf(x4.z, w4.z, acc[r]);
            acc[r] = fmaf(x4.w, w4.w, acc[r]);
        }
    }

#pragma unroll
    for (int r = 0; r < 16; ++r) {
        float y = acc[r];
        float v = 0.f;
        int sp[4];
#pragma unroll
        for (int t = 0; t < 4; ++t) {
            v = v + (y - v) * 0.5f;          // decay_input charge, tau=2
            int s = (v - 1.0f >= 0.f) ? 1 : 0;
            v = s ? 0.f : v;                  // hard reset
            sp[t] = s;
        }
        const int row = r0 + r;
        const int bb = row >> 10;
        const int ss = row & 1023;
        u64* dst = bits + ((((size_t)bz * 4) * 2 + bb) * 8 + by) * 1024 + ss;
#pragma unroll
        for (int t = 0; t < 4; ++t) {
            u64 m = __ballot(sp[t]);
            if (lane == 0) dst[(size_t)t * (2 * 8 * 1024)] = m;
        }
    }
}

// ---------------- Kernel T: bit-transpose of v spikes: vt[b][h][t][w][d]
__global__ __launch_bounds__(256) void v_transpose(
    const u64* __restrict__ bits,
    u64* __restrict__ vt)
{
    const int lane = threadIdx.x & 63;
    const int t = threadIdx.x >> 6;        // one wave per timestep
    const int b = blockIdx.x;
    const int h = blockIdx.y;
    const u64* src = bits + ((((size_t)2 * 4 + t) * 2 + b) * 8 + h) * 1024;
    u64* dst = vt + (((size_t)b * 8 + h) * 4 + t) * 1024;
    for (int w = 0; w < 16; ++w) {
        u64 vword = src[(w << 6) + lane];
#pragma unroll
        for (int d = 0; d < 64; ++d) {
            u64 m = __ballot((int)((vword >> d) & 1ull));
            if (lane == d) dst[(w << 6) + d] = m;
        }
    }
}

// ---------------- Kernel B: scores=popcnt(q&k)/8 -> LIF -> softmax -> @v -> mean_t
__global__ __launch_bounds__(256) void spike_attn(
    const u64* __restrict__ bits,
    const u64* __restrict__ vt,
    float* __restrict__ out)
{
    const int lane = threadIdx.x & 63;
    const int wave = threadIdx.x >> 6;
    const int rt = blockIdx.x;   // 0..31, 32 rows per block
    const int h  = blockIdx.y;
    const int b  = blockIdx.z;

    __shared__ u64 kb_s[4][1024];     // 32 KiB
    __shared__ u64 vt_s[4][16][64];   // 32 KiB

    for (int t = 0; t < 4; ++t) {
        const u64* src = bits + ((((size_t)1 * 4 + t) * 2 + b) * 8 + h) * 1024;
        for (int i = threadIdx.x; i < 1024; i += 256) kb_s[t][i] = src[i];
    }
    {
        const u64* src = vt + (((size_t)b * 8 + h) * 4) * 1024;
        for (int i = threadIdx.x; i < 4096; i += 256) ((u64*)vt_s)[i] = src[i];
    }
    __syncthreads();

    float colcnt[4];   // lane == d
#pragma unroll
    for (int t = 0; t < 4; ++t) {
        int cs = 0;
#pragma unroll
        for (int w = 0; w < 16; ++w) cs += __popcll(vt_s[t][w][lane]);
        colcnt[t] = (float)cs;
    }

    const float E1 = 0.36787944117144233f;  // expf(-1)

    for (int rr = 0; rr < 8; ++rr) {
        const int s = (rt << 5) + (wave << 3) + rr;
        u64 qw[4];
#pragma unroll
        for (int t = 0; t < 4; ++t)
            qw[t] = bits[(((size_t)t * 2 + b) * 8 + h) * 1024 + s];

        int N11[4] = {0, 0, 0, 0};
        int m[4]   = {0, 0, 0, 0};
        for (int w = 0; w < 16; ++w) {
            float v = 0.f;   // LIF state for this (row, k=w*64+lane)
#pragma unroll
            for (int t = 0; t < 4; ++t) {
                int pc = __popcll(qw[t] & kb_s[t][(w << 6) + lane]);
                float sc = (float)pc * 0.125f;     // exact: /sqrt(64)
                v = v + (sc - v) * 0.5f;
                int spk = (v - 1.0f >= 0.f) ? 1 : 0;
                v = spk ? 0.f : v;
                u64 mask = __ballot(spk);
                m[t]   += (int)__popcll(mask);
                N11[t] += (int)__popcll(mask & vt_s[t][w][lane]);
            }
        }

        float o = 0.f;
#pragma unroll
        for (int t = 0; t < 4; ++t) {
            float mf = (float)m[t];
            float Z  = mf + (1024.f - mf) * E1;   // sum of exp(score - max)
            float p1 = 1.0f / Z;
            float p0 = E1 / Z;                    // exact 1/1024 when m==0
            o += p0 * colcnt[t] + (p1 - p0) * (float)N11[t];
        }
        out[((size_t)b * 1024 + s) * 512 + (h << 6) + lane] = o * 0.25f;
    }
}

extern "C" void kernel_launch(void* const* d_in, const int* in_sizes, int n_in,
                              void* d_out, int out_size, void* d_ws, size_t ws_size,
                              hipStream_t stream) {
    const float* x  = (const float*)d_in[0];
    const float* Wq = (const float*)d_in[1];
    const float* Wk = (const float*)d_in[2];
    const float* Wv = (const float*)d_in[3];
    float* out = (float*)d_out;

    u64* bits = (u64*)d_ws;                          // 3*4*2*8*1024 words = 1.5 MiB
    u64* vt   = bits + (size_t)3 * 4 * 2 * 8 * 1024; // 2*8*4*16*64 words = 0.5 MiB

    gemm_lif_pack<<<dim3(32, 8, 3), 256, 0, stream>>>(x, Wq, Wk, Wv, bits);
    v_transpose<<<dim3(2, 8), 256, 0, stream>>>(bits, vt);
    spike_attn<<<dim3(32, 8, 2), 256, 0, stream>>>(bits, vt, out);
}

// Round 2
// 151.518 us; speedup vs baseline: 1.2290x; 1.2290x over previous
//
#include <hip/hip_runtime.h>
#include <cstdint>

typedef unsigned long long u64;

// Dims: B=2, S=1024, C=512, H=8, hd=64, T=4.
// bits layout: [3(qkv)][4(t)][2(b)][8(h)][1024(s)] u64 (bit d = channel h*64+d)
// vt   layout: [2(b)][8(h)][4(t)][16(w)][64(d)]  u64 (bit j = k-index w*64+j)

// ---------------- Kernel A: y = x @ W^T, LIF(4 steps, constant drive), pack bits
__global__ __launch_bounds__(256) void gemm_lif_pack(
    const float* __restrict__ x,    // [2048][512]
    const float* __restrict__ Wq,
    const float* __restrict__ Wk,
    const float* __restrict__ Wv,
    u64* __restrict__ bits)
{
    const int lane = threadIdx.x & 63;
    const int wave = __builtin_amdgcn_readfirstlane(threadIdx.x >> 6);
    const int bx = blockIdx.x;   // row tile of 64 (M = 2048)
    const int by = blockIdx.y;   // head == 64-channel tile
    const int bz = blockIdx.z;   // 0=q 1=k 2=v
    const float* W = (bz == 0) ? Wq : (bz == 1) ? Wk : Wv;

    const int c  = (by << 6) + lane;          // output channel (lane = bit d)
    const int r0 = (bx << 6) + (wave << 4);   // first of 16 rows for this wave

    const float* __restrict__ wrow = W + (size_t)c * 512;
    const float* __restrict__ xrow = x + (size_t)r0 * 512;

    float acc[16];
#pragma unroll
    for (int r = 0; r < 16; ++r) acc[r] = 0.f;

    for (int k = 0; k < 512; k += 4) {
        const float4 w4 = *(const float4*)(wrow + k);
#pragma unroll
        for (int r = 0; r < 16; ++r) {
            const float4 x4 = *(const float4*)(xrow + (size_t)r * 512 + k);
            acc[r] = fmaf(x4.x, w4.x, acc[r]);
            acc[r] = fmaf(x4.y, w4.y, acc[r]);
            acc[r] = fmaf(x4.z, w4.z, acc[r]);
            acc[r] = fmaf(x4.w, w4.w, acc[r]);
        }
    }

#pragma unroll
    for (int r = 0; r < 16; ++r) {
        float y = acc[r];
        float v = 0.f;
        int sp[4];
#pragma unroll
        for (int t = 0; t < 4; ++t) {
            v = v + (y - v) * 0.5f;          // decay_input charge, tau=2
            int s = (v - 1.0f >= 0.f) ? 1 : 0;
            v = s ? 0.f : v;                  // hard reset
            sp[t] = s;
        }
        const int row = r0 + r;
        const int bb = row >> 10;
        const int ss = row & 1023;
        u64* dst = bits + ((((size_t)bz * 4) * 2 + bb) * 8 + by) * 1024 + ss;
#pragma unroll
        for (int t = 0; t < 4; ++t) {
            u64 m = __ballot(sp[t]);
            if (lane == 0) dst[(size_t)t * (2 * 8 * 1024)] = m;
        }
    }
}

// ---------------- Kernel T: bit-transpose of v spikes: vt[b][h][t][w][d]
__global__ __launch_bounds__(256) void v_transpose(
    const u64* __restrict__ bits,
    u64* __restrict__ vt)
{
    const int lane = threadIdx.x & 63;
    const int t = threadIdx.x >> 6;        // one wave per timestep
    const int b = blockIdx.x;
    const int h = blockIdx.y;
    const u64* src = bits + ((((size_t)2 * 4 + t) * 2 + b) * 8 + h) * 1024;
    u64* dst = vt + (((size_t)b * 8 + h) * 4 + t) * 1024;
    for (int w = 0; w < 16; ++w) {
        u64 vword = src[(w << 6) + lane];
#pragma unroll
        for (int d = 0; d < 64; ++d) {
            u64 m = __ballot((int)((vword >> d) & 1ull));
            if (lane == d) dst[(w << 6) + d] = m;
        }
    }
}

// ---------------- Kernel B v2: no LDS, integer LIF, uniform fast/slow path.
// scores = popcnt(q&k)/8 -> LIF -> softmax(binary row) -> @v -> mean over t.
// Integer LIF in 64ths: u = (u>>1) + (pc<<2), spike iff u >= 64.
// Exactness: with V = state in 128ths (integer), u = floor(V/2) is invariant
// under the recurrence and resets, and V>=128 <=> floor(V/2)>=64 for integer V.
// Fast path computes the no-reset chain (a monotone upper bound): if no lane
// crosses threshold there, no true spike exists -> skip reset/m/N11 entirely.
__global__ __launch_bounds__(256) void spike_attn2(
    const u64* __restrict__ bits,
    const u64* __restrict__ vt,
    float* __restrict__ out)
{
    const int lane = threadIdx.x & 63;
    const int wave = __builtin_amdgcn_readfirstlane((int)(threadIdx.x >> 6));
    const int rt = blockIdx.x;   // 64 tiles of 16 rows
    const int h  = blockIdx.y;
    const int b  = blockIdx.z;

    const int bh = b * 8 + h;
    const u64* __restrict__ qb  = bits + (size_t)bh * 1024;         // + t*16384 + s
    const u64* __restrict__ kb  = bits + (size_t)(64 + bh) * 1024;  // + t*16384 + k
    const u64* __restrict__ vtb = vt + (size_t)bh * 4096;           // + t*1024 + w*64 + d

    // column counts of v spikes (lane = d), per t
    int cs[4] = {0, 0, 0, 0};
    for (int w = 0; w < 16; ++w) {
#pragma unroll
        for (int t = 0; t < 4; ++t)
            cs[t] += (int)__popcll(vtb[t * 1024 + (w << 6) + lane]);
    }

    const int s0 = rt * 16 + wave * 4;   // 4 rows per wave

    u64 qw[4][4];                         // wave-uniform row words
#pragma unroll
    for (int r = 0; r < 4; ++r)
#pragma unroll
        for (int t = 0; t < 4; ++t)
            qw[r][t] = qb[t * 16384 + s0 + r];

    int n11[4][4];
    int msum[4][4];
#pragma unroll
    for (int r = 0; r < 4; ++r)
#pragma unroll
        for (int t = 0; t < 4; ++t) { n11[r][t] = 0; msum[r][t] = 0; }

    for (int w = 0; w < 16; ++w) {
        const int ko = (w << 6) + lane;
        u64 kw0 = kb[0 * 16384 + ko];
        u64 kw1 = kb[1 * 16384 + ko];
        u64 kw2 = kb[2 * 16384 + ko];
        u64 kw3 = kb[3 * 16384 + ko];

#pragma unroll
        for (int r = 0; r < 4; ++r) {
            const int pc0 = (int)__popcll(kw0 & qw[r][0]);
            const int pc1 = (int)__popcll(kw1 & qw[r][1]);
            const int pc2 = (int)__popcll(kw2 & qw[r][2]);
            const int pc3 = (int)__popcll(kw3 & qw[r][3]);

            unsigned u = (unsigned)(pc0 << 2);
            u64 b0 = __ballot(u >= 64u);
            u = (u >> 1) + (unsigned)(pc1 << 2);
            u64 b1 = __ballot(u >= 64u);
            u = (u >> 1) + (unsigned)(pc2 << 2);
            u64 b2 = __ballot(u >= 64u);
            u = (u >> 1) + (unsigned)(pc3 << 2);
            u64 b3 = __ballot(u >= 64u);

            if (b0 | b1 | b2 | b3) {      // uniform, essentially never taken
                const int pcs[4] = {pc0, pc1, pc2, pc3};
                unsigned v = 0;
#pragma unroll
                for (int t = 0; t < 4; ++t) {
                    v = (v >> 1) + (unsigned)(pcs[t] << 2);
                    const int spk = (v >= 64u) ? 1 : 0;
                    u64 msk = __ballot(spk);
                    v = spk ? 0u : v;
                    msum[r][t] += (int)__popcll(msk);
                    n11[r][t]  += (int)__popcll(msk & vtb[t * 1024 + (w << 6) + lane]);
                }
            }
        }
    }

    const float E1 = 0.36787944117144233f;  // expf(-1)
#pragma unroll
    for (int r = 0; r < 4; ++r) {
        float o = 0.f;
#pragma unroll
        for (int t = 0; t < 4; ++t) {
            const float mf = (float)msum[r][t];
            const float Z  = mf + (1024.f - mf) * E1;  // softmax denom (max-shifted)
            const float p1 = 1.0f / Z;
            const float p0 = E1 / Z;                   // exactly 1/1024 when m==0
            o += p0 * (float)cs[t] + (p1 - p0) * (float)n11[r][t];
        }
        out[((size_t)b * 1024 + (s0 + r)) * 512 + (h << 6) + lane] = o * 0.25f;
    }
}

extern "C" void kernel_launch(void* const* d_in, const int* in_sizes, int n_in,
                              void* d_out, int out_size, void* d_ws, size_t ws_size,
                              hipStream_t stream) {
    const float* x  = (const float*)d_in[0];
    const float* Wq = (const float*)d_in[1];
    const float* Wk = (const float*)d_in[2];
    const float* Wv = (const float*)d_in[3];
    float* out = (float*)d_out;

    u64* bits = (u64*)d_ws;                          // 3*4*2*8*1024 words = 1.5 MiB
    u64* vt   = bits + (size_t)3 * 4 * 2 * 8 * 1024; // 2*8*4*16*64 words = 0.5 MiB

    gemm_lif_pack<<<dim3(32, 8, 3), 256, 0, stream>>>(x, Wq, Wk, Wv, bits);
    v_transpose<<<dim3(2, 8), 256, 0, stream>>>(bits, vt);
    spike_attn2<<<dim3(64, 8, 2), 256, 0, stream>>>(bits, vt, out);
}

// Round 3
// 138.017 us; speedup vs baseline: 1.3493x; 1.0978x over previous
//
#include <hip/hip_runtime.h>
#include <cstdint>

typedef unsigned long long u64;

#define RFL(x) __builtin_amdgcn_readfirstlane(x)

// Dims: B=2, S=1024, C=512, H=8, hd=64, T=4.
// bits layout: [3(qkv)][4(t)][2(b)][8(h)][1024(s)] u64 (bit d = channel h*64+d)
// vt   layout: [2(b)][8(h)][4(t)][16(w)][64(d)]  u64 (bit j = k-index w*64+j)
// ws usage: bits 1.5 MiB + vt 0.5 MiB = 2.0 MiB exactly (unchanged from R1/R2).

// ---------------- Kernel A2: fused y = x@{Wq,Wk,Wv}^T, LIF, pack bits.
// lane = output channel within head (by); 8 rows per wave, 32 per block.
// W staged per-32k-chunk in LDS, coalesced, layout [k][ch] (bank-conflict-free).
// x rows are wave-uniform -> scalar loads. FMA order = ascending k, identical
// to previous rounds -> bitwise-identical y -> spike decisions unchanged.
__global__ __launch_bounds__(256) void gemm_lif_pack2(
    const float* __restrict__ x,    // [2048][512]
    const float* __restrict__ Wq,
    const float* __restrict__ Wk,
    const float* __restrict__ Wv,
    u64* __restrict__ bits)
{
    __shared__ float wlds[3][32][64];   // 24 KiB

    const int tid  = threadIdx.x;
    const int lane = tid & 63;
    const int wave = RFL(tid >> 6);
    const int bx = blockIdx.x;          // 64 tiles of 32 rows
    const int by = blockIdx.y;          // head
    const int r0 = bx * 32 + wave * 8;  // 8 rows for this wave

    const float* __restrict__ xr = x + (size_t)r0 * 512;
    const float* Wm[3] = {Wq, Wk, Wv};

    float acc[3][8];
#pragma unroll
    for (int m = 0; m < 3; ++m)
#pragma unroll
        for (int r = 0; r < 8; ++r) acc[m][r] = 0.f;

    for (int k0 = 0; k0 < 512; k0 += 32) {
        // ---- stage W chunk: 3 x 64ch x 32k, coalesced float4 loads
#pragma unroll
        for (int m = 0; m < 3; ++m) {
            const float* __restrict__ Wsrc = Wm[m] + (size_t)(by * 64) * 512 + k0;
#pragma unroll
            for (int p = 0; p < 2; ++p) {
                const int fi = p * 256 + tid;   // float4 index 0..511
                const int ch = fi >> 3;         // 8 float4 per channel row
                const int kq = fi & 7;
                const float4 v4 = *(const float4*)(Wsrc + (size_t)ch * 512 + kq * 4);
                wlds[m][kq * 4 + 0][ch] = v4.x;
                wlds[m][kq * 4 + 1][ch] = v4.y;
                wlds[m][kq * 4 + 2][ch] = v4.z;
                wlds[m][kq * 4 + 3][ch] = v4.w;
            }
        }
        __syncthreads();

        // ---- compute 32 k-steps
#pragma unroll
        for (int g = 0; g < 8; ++g) {
            const int kk = g * 4;
            float w0[3], w1[3], w2[3], w3[3];
#pragma unroll
            for (int m = 0; m < 3; ++m) {
                w0[m] = wlds[m][kk + 0][lane];
                w1[m] = wlds[m][kk + 1][lane];
                w2[m] = wlds[m][kk + 2][lane];
                w3[m] = wlds[m][kk + 3][lane];
            }
#pragma unroll
            for (int r = 0; r < 8; ++r) {
                const float4 x4 = *(const float4*)(xr + (size_t)r * 512 + k0 + kk);
#pragma unroll
                for (int m = 0; m < 3; ++m) {
                    acc[m][r] = fmaf(x4.x, w0[m], acc[m][r]);
                    acc[m][r] = fmaf(x4.y, w1[m], acc[m][r]);
                    acc[m][r] = fmaf(x4.z, w2[m], acc[m][r]);
                    acc[m][r] = fmaf(x4.w, w3[m], acc[m][r]);
                }
            }
        }
        __syncthreads();
    }

    // ---- LIF + ballot pack
#pragma unroll
    for (int m = 0; m < 3; ++m) {
#pragma unroll
        for (int r = 0; r < 8; ++r) {
            const float y = acc[m][r];
            float v = 0.f;
            int sp[4];
#pragma unroll
            for (int t = 0; t < 4; ++t) {
                v = v + (y - v) * 0.5f;           // decay_input charge, tau=2
                const int s = (v - 1.0f >= 0.f) ? 1 : 0;
                v = s ? 0.f : v;                  // hard reset
                sp[t] = s;
            }
            const int row = r0 + r;
            const int bb = row >> 10;
            const int ss = row & 1023;
            u64* dst = bits + (((size_t)(m * 4) * 2 + bb) * 8 + by) * 1024 + ss;
#pragma unroll
            for (int t = 0; t < 4; ++t) {
                const u64 msk = __ballot(sp[t]);
                if (lane == 0) dst[(size_t)t * (2 * 8 * 1024)] = msk;
            }
        }
    }
}

// ---------------- Kernel T2: bit-transpose of v spikes (w-split, coalesced store)
__global__ __launch_bounds__(256) void v_transpose2(
    const u64* __restrict__ bits,
    u64* __restrict__ vt)
{
    const int lane = threadIdx.x & 63;
    const int t  = threadIdx.x >> 6;      // one wave per timestep
    const int b  = blockIdx.x;
    const int h  = blockIdx.y;
    const int wg = blockIdx.z;            // 4 w's per block
    const u64* __restrict__ src = bits + (((size_t)(2 * 4 + t) * 2 + b) * 8 + h) * 1024;
    u64* __restrict__ dst = vt + (((size_t)b * 8 + h) * 4 + t) * 1024;
    for (int wi = 0; wi < 4; ++wi) {
        const int w = wg * 4 + wi;
        const u64 vword = src[(w << 6) + lane];
        u64 myword = 0;
#pragma unroll
        for (int d = 0; d < 64; ++d) {
            const u64 m = __ballot((int)((vword >> d) & 1ull));
            if (lane == d) myword = m;
        }
        dst[(w << 6) + lane] = myword;    // coalesced
    }
}

// ---------------- Kernel B3: exact q-row filter + integer LIF slow path.
// Score spike at (s,k,t) requires u>=64 with u <= 7.5*max_t pc_t (no-reset
// upper bound) and pc_t <= popcount(q_t[s]); so max_t popcount(q_t[s]) <= 8
// implies NO spike for row s against any k -> output = sum_t cs_t * 2^-12
// (exactly equal to the reference softmax@V in that case, shown in journal).
__global__ __launch_bounds__(256) void spike_attn3(
    const u64* __restrict__ bits,
    const u64* __restrict__ vt,
    float* __restrict__ out)
{
    const int lane = threadIdx.x & 63;
    const int wave = RFL((int)(threadIdx.x >> 6));
    const int rt = blockIdx.x;   // 32 tiles of 32 rows
    const int h  = blockIdx.y;
    const int b  = blockIdx.z;

    const int bh = b * 8 + h;
    const u64* __restrict__ qb  = bits + (size_t)bh * 1024;         // + t*16384 + s
    const u64* __restrict__ kb  = bits + (size_t)(64 + bh) * 1024;  // + t*16384 + k
    const u64* __restrict__ vtb = vt + (size_t)bh * 4096;           // + t*1024 + w*64 + d

    // column counts of v spikes (lane = d), per t
    int cs[4] = {0, 0, 0, 0};
    for (int w = 0; w < 16; ++w) {
#pragma unroll
        for (int t = 0; t < 4; ++t)
            cs[t] += (int)__popcll(vtb[t * 1024 + (w << 6) + lane]);
    }
    const float base = (float)(cs[0] + cs[1] + cs[2] + cs[3]) * (1.0f / 4096.0f);

    const float E1 = 0.36787944117144233f;  // expf(-1)
    const int s0 = rt * 32 + wave * 8;      // 8 rows per wave

    for (int r = 0; r < 8; ++r) {
        const int s = s0 + r;
        const u64 q0 = qb[s];
        const u64 q1 = qb[16384 + s];
        const u64 q2 = qb[32768 + s];
        const u64 q3 = qb[49152 + s];
        const int c0 = (int)__popcll(q0), c1 = (int)__popcll(q1);
        const int c2 = (int)__popcll(q2), c3 = (int)__popcll(q3);
        const int mx = max(max(c0, c1), max(c2, c3));

        float o = base;
        if (mx >= 9) {   // wave-uniform, essentially never taken; exact path
            int msum[4] = {0, 0, 0, 0}, n11[4] = {0, 0, 0, 0};
            for (int w = 0; w < 16; ++w) {
                const int ko = (w << 6) + lane;
                const u64 kw0 = kb[ko];
                const u64 kw1 = kb[16384 + ko];
                const u64 kw2 = kb[32768 + ko];
                const u64 kw3 = kb[49152 + ko];
                const int pcs[4] = {
                    (int)__popcll(kw0 & q0), (int)__popcll(kw1 & q1),
                    (int)__popcll(kw2 & q2), (int)__popcll(kw3 & q3)};
                unsigned u = 0;
#pragma unroll
                for (int t = 0; t < 4; ++t) {
                    u = (u >> 1) + (unsigned)(pcs[t] << 2);  // 64ths; exact
                    const int spk = (u >= 64u) ? 1 : 0;
                    const u64 msk = __ballot(spk);
                    u = spk ? 0u : u;
                    msum[t] += (int)__popcll(msk);
                    n11[t]  += (int)__popcll(msk & vtb[t * 1024 + ko]);
                }
            }
            o = 0.f;
#pragma unroll
            for (int t = 0; t < 4; ++t) {
                const float mf = (float)msum[t];
                const float Z  = mf + (1024.f - mf) * E1;
                const float p1 = 1.0f / Z;
                const float p0 = E1 / Z;                 // exactly 2^-10 when m==0
                o += p0 * (float)cs[t] + (p1 - p0) * (float)n11[t];
            }
            o *= 0.25f;
        }
        out[((size_t)b * 1024 + s) * 512 + (h << 6) + lane] = o;
    }
}

extern "C" void kernel_launch(void* const* d_in, const int* in_sizes, int n_in,
                              void* d_out, int out_size, void* d_ws, size_t ws_size,
                              hipStream_t stream) {
    const float* x  = (const float*)d_in[0];
    const float* Wq = (const float*)d_in[1];
    const float* Wk = (const float*)d_in[2];
    const float* Wv = (const float*)d_in[3];
    float* out = (float*)d_out;

    u64* bits = (u64*)d_ws;                          // 1.5 MiB
    u64* vt   = bits + (size_t)3 * 4 * 2 * 8 * 1024; // 0.5 MiB

    gemm_lif_pack2<<<dim3(64, 8), 256, 0, stream>>>(x, Wq, Wk, Wv, bits);
    v_transpose2<<<dim3(2, 8, 4), 256, 0, stream>>>(bits, vt);
    spike_attn3<<<dim3(32, 8, 2), 256, 0, stream>>>(bits, vt, out);
}